// Round 12
// baseline (288.445 us; speedup 1.0000x reference)
//
#include <hip/hip_runtime.h>
#include <stdint.h>

typedef unsigned short u16;
using bf16x8 = __attribute__((ext_vector_type(8))) short;
using f32x4  = __attribute__((ext_vector_type(4))) float;

#define NORM 0.03125f  // 1/sqrt(1024)

enum { M_PROJ = 0, M_EXP = 1 };
enum { M_PV = 0, M_OUT = 1 };

__device__ __forceinline__ u16 f2bf(float f) {
  uint32_t u = __float_as_uint(f);
  return (u16)((u + 0x7FFFu + ((u >> 16) & 1u)) >> 16);  // RNE
}

__device__ __forceinline__ void gload_lds16(const void* g, void* lds) {
  __builtin_amdgcn_global_load_lds(
      (const __attribute__((address_space(1))) uint32_t*)g,
      (__attribute__((address_space(3))) uint32_t*)lds, 16, 0, 0);
}

// transpose + convert the 4 weight matrices [1024x1024] f32 -> WT[n][k] bf16
__global__ void k_tc(const float* __restrict__ W0, const float* __restrict__ W1,
                     const float* __restrict__ W2, const float* __restrict__ W3,
                     u16* __restrict__ dst) {
  __shared__ float t[64][65];
  const float* W = blockIdx.z == 0 ? W0 : blockIdx.z == 1 ? W1 : blockIdx.z == 2 ? W2 : W3;
  u16* WT = dst + (size_t)blockIdx.z * (1024 * 1024);
  int c0 = blockIdx.x * 64, r0 = blockIdx.y * 64;
  int c = threadIdx.x & 63, q = threadIdx.x >> 6;
  for (int r = q; r < 64; r += 4) t[r][c] = W[(size_t)(r0 + r) * 1024 + c0 + c];
  __syncthreads();
  for (int r = q; r < 64; r += 4) WT[(size_t)(c0 + r) * 1024 + r0 + c] = f2bf(t[c][r]);
}

struct GArgs {
  const u16* A; const u16* B; int lda, ldb; long long bstrideB; int K;
  const float* bias; const float* adj; float* dpart; const float* dpart_r;
  void* C; int ldc;
  const float* Af0; const float* Af1;            // f32 A sources (PROJ)
  const u16* B1; const u16* B2;
  const float* bias1; const float* bias2; void* C1; void* C2;
};

// ---------- 128x128 tile, 4 waves (2x2), 64x64/wave: PROJ & EXP ----------
// LDS 32KB single-buffered, XOR swizzle phys_u16col = c ^ ((row&7)<<3).
// Default dispatch order (x fastest): consecutive blocks share the B-panel;
// A-row traffic is compulsory. NO hand remaps (r10/r11 lesson: bx-major
// XCD chunks give every XCD the full A matrix -> L2 thrash, FETCH 115->181MB).
// PROJ: A staged from f32 source with fused RNE cvt (reg->b128 ds_write,
// bank-conflict-free, measured r9); B via gload_lds. 4 blocks/CU resident;
// latency hidden by inter-block overlap (m114).
template <int MODE>
__global__ __launch_bounds__(256, 4) void gemm_occ(GArgs g) {
  __shared__ __align__(16) u16 As[128 * 64];
  __shared__ __align__(16) u16 Bs[128 * 64];

  const int tid = threadIdx.x;
  const int lane = tid & 63;
  const int wid = tid >> 6;
  const int wr = wid >> 1, wc = wid & 1;

  const int bx = blockIdx.x, by = blockIdx.y;
  const int m0 = bx * 128;
  const int n0 = by * 128;
  const int b = m0 >> 11;  // 2048 rows per batch

  const u16* B = g.B;
  const float* bias = g.bias; void* C = g.C;
  const float* Af = g.Af0;
  int zmode = 0;
  if constexpr (MODE == M_PROJ) {
    int z = blockIdx.z; zmode = z;
    if (z == 1) { Af = g.Af1; B = g.B1; bias = g.bias1; C = g.C1; }
    else if (z == 2) { Af = g.Af1; B = g.B2; bias = g.bias2; C = g.C2; }
  }
  const int lda = g.lda, ldb = g.ldb, K = g.K;
  const u16* Bp = B + (size_t)b * g.bstrideB;

  f32x4 acc[4][4] = {};

  const int ric = lane >> 3;         // row within 8-row chunk
  const int c8 = (lane & 7) * 8;     // u16 col granule (16B)
  const int fr = lane & 15;
  const int hi = lane >> 4;

  for (int kt = 0; kt < K; kt += 64) {
    if constexpr (MODE == M_PROJ) {
      // B: 16 chunks via gload_lds
#pragma unroll
      for (int c = 0; c < 4; ++c) {
        int ch = wid * 4 + c;
        int row = ch * 8 + ric;
        int swc = c8 ^ ((row & 7) << 3);
        gload_lds16(Bp + (size_t)(n0 + row) * ldb + kt + swc, (void*)&Bs[ch * 512]);
      }
      // A: fused f32->bf16 staging, 4 passes x one b128 granule/thread
#pragma unroll
      for (int p = 0; p < 4; ++p) {
        int row = p * 32 + (tid >> 3);
        int cc = (tid & 7) * 8;
        const float* src = &Af[(size_t)(m0 + row) * 1024 + kt + cc];
        float4 v0 = *(const float4*)src;
        float4 v1 = *(const float4*)(src + 4);
        uint4 pk;
        pk.x = f2bf(v0.x) | ((uint32_t)f2bf(v0.y) << 16);
        pk.y = f2bf(v0.z) | ((uint32_t)f2bf(v0.w) << 16);
        pk.z = f2bf(v1.x) | ((uint32_t)f2bf(v1.y) << 16);
        pk.w = f2bf(v1.z) | ((uint32_t)f2bf(v1.w) << 16);
        *(uint4*)&As[row * 64 + (cc ^ ((row & 7) << 3))] = pk;
      }
    } else {
#pragma unroll
      for (int c = 0; c < 4; ++c) {
        int ch = wid * 4 + c;
        int row = ch * 8 + ric;
        int swc = c8 ^ ((row & 7) << 3);
        gload_lds16(g.A + (size_t)(m0 + row) * lda + kt + swc, (void*)&As[ch * 512]);
        gload_lds16(Bp + (size_t)(n0 + row) * ldb + kt + swc, (void*)&Bs[ch * 512]);
      }
    }
    __syncthreads();
#pragma unroll
    for (int kk = 0; kk < 64; kk += 32) {
      bf16x8 af[4], bfr[4];
#pragma unroll
      for (int m = 0; m < 4; ++m) {
        int row = wr * 64 + m * 16 + fr;
        af[m] = *(const bf16x8*)__builtin_assume_aligned(
            &As[row * 64 + ((kk + hi * 8) ^ ((row & 7) << 3))], 16);
      }
#pragma unroll
      for (int n = 0; n < 4; ++n) {
        int row = wc * 64 + n * 16 + fr;
        bfr[n] = *(const bf16x8*)__builtin_assume_aligned(
            &Bs[row * 64 + ((kk + hi * 8) ^ ((row & 7) << 3))], 16);
      }
#pragma unroll
      for (int m = 0; m < 4; ++m)
#pragma unroll
        for (int n = 0; n < 4; ++n)
          acc[m][n] = __builtin_amdgcn_mfma_f32_16x16x32_bf16(af[m], bfr[n], acc[m][n], 0, 0, 0);
    }
    __syncthreads();
  }

  // C layout (m89-verified): col = lane&15, row = (lane>>4)*4 + reg
  const int lr = lane >> 4;
  const int lc = lane & 15;

  if constexpr (MODE == M_PROJ) {
    if (zmode < 2) {
      u16* Cc = (u16*)C;
#pragma unroll
      for (int m = 0; m < 4; ++m)
#pragma unroll
        for (int n = 0; n < 4; ++n) {
          int gcol = n0 + wc * 64 + n * 16 + lc;
          float bv = bias[gcol];
#pragma unroll
          for (int r = 0; r < 4; ++r) {
            int grow = m0 + wr * 64 + m * 16 + lr * 4 + r;
            Cc[(size_t)grow * g.ldc + gcol] = f2bf(acc[m][n][r] + bv);
          }
        }
    } else {  // V: store transposed Vt[b][d][t]
      u16* Cc = (u16*)C;
#pragma unroll
      for (int m = 0; m < 4; ++m) {
        int grow0 = m0 + wr * 64 + m * 16 + lr * 4;
        int t0 = grow0 & 2047;
#pragma unroll
        for (int n = 0; n < 4; ++n) {
          int gcol = n0 + wc * 64 + n * 16 + lc;
          float bv = bias[gcol];
          ushort4 pk = make_ushort4(f2bf(acc[m][n][0] + bv), f2bf(acc[m][n][1] + bv),
                                    f2bf(acc[m][n][2] + bv), f2bf(acc[m][n][3] + bv));
          *(ushort4*)&Cc[((size_t)b * 1024 + gcol) * 2048 + t0] = pk;
        }
      }
    }
  } else {  // M_EXP
    u16* Cc = (u16*)C;  // E [8192][2048]
    float esum[4][4] = {};
#pragma unroll
    for (int m = 0; m < 4; ++m)
#pragma unroll
      for (int n = 0; n < 4; ++n) {
        int gcol = n0 + wc * 64 + n * 16 + lc;
#pragma unroll
        for (int r = 0; r < 4; ++r) {
          int grow = m0 + wr * 64 + m * 16 + lr * 4 + r;
          float z = acc[m][n][r] * NORM + g.adj[(size_t)grow * 2048 + gcol];
          float e = __expf(z);
          Cc[(size_t)grow * 2048 + gcol] = f2bf(e);
          esum[m][r] += e;
        }
      }
    int pidx = by * 2 + wc;  // 16 t-tiles x 2 wave-cols = 32 partials
#pragma unroll
    for (int m = 0; m < 4; ++m)
#pragma unroll
      for (int r = 0; r < 4; ++r) {
        float s = esum[m][r];
        s += __shfl_xor(s, 1); s += __shfl_xor(s, 2);
        s += __shfl_xor(s, 4); s += __shfl_xor(s, 8);
        if (lc == 0)
          g.dpart[(size_t)pidx * 8192 + (m0 + wr * 64 + m * 16 + lr * 4 + r)] = s;
      }
  }
}

// ---------- 128x64 tile, 4 waves (each 32m x 64n): PV & OUT ----------
// Full-residency variant for the narrow-N GEMMs: grid (64,16) = 1024
// blocks -> 4 blocks/CU. LDS 24KB. Default dispatch order.
template <int MODE>
__global__ __launch_bounds__(256, 4) void gemm64(GArgs g) {
  __shared__ __align__(16) u16 As[128 * 64];
  __shared__ __align__(16) u16 Bs[64 * 64];

  const int tid = threadIdx.x;
  const int lane = tid & 63;
  const int wid = tid >> 6;

  const int bx = blockIdx.x, by = blockIdx.y;
  const int m0 = bx * 128;
  const int n0 = by * 64;
  const int b = m0 >> 11;

  const int lda = g.lda, ldb = g.ldb, K = g.K;
  const u16* Bp = g.B + (size_t)b * g.bstrideB;

  f32x4 acc[2][4] = {};

  const int ric = lane >> 3;
  const int c8 = (lane & 7) * 8;
  const int fr = lane & 15;
  const int hi = lane >> 4;

  for (int kt = 0; kt < K; kt += 64) {
#pragma unroll
    for (int c = 0; c < 4; ++c) {
      int ch = wid * 4 + c;          // A: 16 chunks
      int row = ch * 8 + ric;
      int swc = c8 ^ ((row & 7) << 3);
      gload_lds16(g.A + (size_t)(m0 + row) * lda + kt + swc, (void*)&As[ch * 512]);
    }
#pragma unroll
    for (int c = 0; c < 2; ++c) {
      int ch = wid * 2 + c;          // B: 8 chunks
      int row = ch * 8 + ric;
      int swc = c8 ^ ((row & 7) << 3);
      gload_lds16(Bp + (size_t)(n0 + row) * ldb + kt + swc, (void*)&Bs[ch * 512]);
    }
    __syncthreads();
#pragma unroll
    for (int kk = 0; kk < 64; kk += 32) {
      bf16x8 af[2], bfr[4];
#pragma unroll
      for (int m = 0; m < 2; ++m) {
        int row = wid * 32 + m * 16 + fr;
        af[m] = *(const bf16x8*)__builtin_assume_aligned(
            &As[row * 64 + ((kk + hi * 8) ^ ((row & 7) << 3))], 16);
      }
#pragma unroll
      for (int n = 0; n < 4; ++n) {
        int row = n * 16 + fr;
        bfr[n] = *(const bf16x8*)__builtin_assume_aligned(
            &Bs[row * 64 + ((kk + hi * 8) ^ ((row & 7) << 3))], 16);
      }
#pragma unroll
      for (int m = 0; m < 2; ++m)
#pragma unroll
        for (int n = 0; n < 4; ++n)
          acc[m][n] = __builtin_amdgcn_mfma_f32_16x16x32_bf16(af[m], bfr[n], acc[m][n], 0, 0, 0);
    }
    __syncthreads();
  }

  const int lr = lane >> 4;
  const int lc = lane & 15;

  if constexpr (MODE == M_PV) {
    __shared__ float dinv[128];
    if (tid < 128) {
      float s = 0.f;
#pragma unroll
      for (int t = 0; t < 32; ++t) s += g.dpart_r[(size_t)t * 8192 + m0 + tid];
      dinv[tid] = 1.0f / s;
    }
    __syncthreads();
    u16* Cc = (u16*)g.C;
#pragma unroll
    for (int m = 0; m < 2; ++m)
#pragma unroll
      for (int n = 0; n < 4; ++n) {
        int gcol = n0 + n * 16 + lc;
#pragma unroll
        for (int r = 0; r < 4; ++r) {
          int lrow = wid * 32 + m * 16 + lr * 4 + r;
          Cc[(size_t)(m0 + lrow) * g.ldc + gcol] = f2bf(acc[m][n][r] * dinv[lrow]);
        }
      }
  } else {  // M_OUT: f32 + bias
    float* Cc = (float*)g.C;
#pragma unroll
    for (int m = 0; m < 2; ++m)
#pragma unroll
      for (int n = 0; n < 4; ++n) {
        int gcol = n0 + n * 16 + lc;
        float bv = g.bias[gcol];
#pragma unroll
        for (int r = 0; r < 4; ++r) {
          int grow = m0 + wid * 32 + m * 16 + lr * 4 + r;
          Cc[(size_t)grow * g.ldc + gcol] = acc[m][n][r] + bv;
        }
      }
  }
}

extern "C" void kernel_launch(void* const* d_in, const int* in_sizes, int n_in,
                              void* d_out, int out_size, void* d_ws, size_t ws_size,
                              hipStream_t stream) {
  const float* x   = (const float*)d_in[0];
  const float* y   = (const float*)d_in[1];
  const float* adj = (const float*)d_in[2];
  const float* Wq  = (const float*)d_in[3];
  const float* bq  = (const float*)d_in[4];
  const float* Wk  = (const float*)d_in[5];
  const float* bk  = (const float*)d_in[6];
  const float* Wv  = (const float*)d_in[7];
  const float* bv  = (const float*)d_in[8];
  const float* Wo  = (const float*)d_in[9];
  const float* bo  = (const float*)d_in[10];
  float* out = (float*)d_out;

  char* ws = (char*)d_ws;
  if (ws_size < 143654912ULL) return;  // need ~137 MB
  u16* WT = (u16*)(ws + 33554432);      // 4 x [1024][1024] (transposed)
  u16* Qb = (u16*)(ws + 41943040);      // [8192][1024]
  u16* Kb = (u16*)(ws + 58720256);      // [8192][1024]
  u16* Vt = (u16*)(ws + 75497472);      // [4][1024][2048] (V transposed)
  u16* E  = (u16*)(ws + 92274688);      // [8192][2048] unnormalized exp
  float* dpart = (float*)(ws + 125829120);  // [32][8192] partial denoms
  u16* tmpb = (u16*)(ws + 126877696);   // [8192][1024] attention output

  u16* WqT = WT;
  u16* WkT = WT + 1048576;
  u16* WvT = WT + 2097152;
  u16* WoT = WT + 3145728;

  k_tc<<<dim3(16, 16, 4), 256, 0, stream>>>(Wq, Wk, Wv, Wo, WT);

  GArgs ga = {};
  // fused cvt + Q/K/V projections; (64,8,3) default order
  ga.lda = 1024; ga.ldb = 1024; ga.bstrideB = 0; ga.K = 1024;
  ga.B = WqT; ga.bias = bq; ga.C = Qb; ga.ldc = 1024;
  ga.Af0 = x; ga.Af1 = y;
  ga.B1 = WkT; ga.B2 = WvT; ga.bias1 = bk; ga.bias2 = bv;
  ga.C1 = Kb; ga.C2 = Vt;
  gemm_occ<M_PROJ><<<dim3(64, 8, 3), 256, 0, stream>>>(ga);

  // E = exp(Q@K^T * norm + adj), partial row sums; (64,16) default order
  GArgs ge = {};
  ge.A = Qb; ge.B = Kb; ge.lda = 1024; ge.ldb = 1024; ge.bstrideB = 2097152LL; ge.K = 1024;
  ge.adj = adj; ge.dpart = dpart; ge.C = E; ge.ldc = 2048;
  gemm_occ<M_EXP><<<dim3(64, 16), 256, 0, stream>>>(ge);

  // tmp = (E @ V) / denom; (64,16) = 1024 blocks (128x64 tiles)
  GArgs gp = {};
  gp.A = E; gp.B = Vt; gp.lda = 2048; gp.ldb = 2048; gp.bstrideB = 2097152LL; gp.K = 2048;
  gp.dpart_r = dpart; gp.C = tmpb; gp.ldc = 1024;
  gemm64<M_PV><<<dim3(64, 16), 256, 0, stream>>>(gp);

  // out = tmp @ Wo + bo (f32); (64,16) = 1024 blocks (128x64 tiles)
  GArgs go = {};
  go.A = tmpb; go.B = WoT; go.lda = 1024; go.ldb = 1024; go.bstrideB = 0; go.K = 1024;
  go.bias = bo; go.C = out; go.ldc = 1024;
  gemm64<M_OUT><<<dim3(64, 16), 256, 0, stream>>>(go);
}

// Round 13
// 256.408 us; speedup vs baseline: 1.1249x; 1.1249x over previous
//
#include <hip/hip_runtime.h>
#include <stdint.h>

typedef unsigned short u16;
using bf16x8 = __attribute__((ext_vector_type(8))) short;
using f32x4  = __attribute__((ext_vector_type(4))) float;

#define NORM 0.03125f  // 1/sqrt(1024)

enum { M_PROJ = 0, M_EXP = 1, M_PV = 2, M_OUT = 3 };

__device__ __forceinline__ u16 f2bf(float f) {
  uint32_t u = __float_as_uint(f);
  return (u16)((u + 0x7FFFu + ((u >> 16) & 1u)) >> 16);  // RNE
}

__device__ __forceinline__ void gload_lds16(const void* g, void* lds) {
  __builtin_amdgcn_global_load_lds(
      (const __attribute__((address_space(1))) uint32_t*)g,
      (__attribute__((address_space(3))) uint32_t*)lds, 16, 0, 0);
}

// bijective XCD remap for 64x16 = 1024-block grids (as benched in r9)
__device__ __forceinline__ void remap1024(int& bx, int& by) {
  int id = bx + (by << 6);
  int nid = ((id & 7) << 7) + (id >> 3);
  bx = nid & 63;
  by = nid >> 6;
}

// f32 -> bf16 elementwise, 4 elems/thread
__global__ void k_cvt(const float* __restrict__ in, u16* __restrict__ out, int n4) {
  int i = blockIdx.x * blockDim.x + threadIdx.x;
  if (i >= n4) return;
  float4 v = ((const float4*)in)[i];
  uint32_t lo = f2bf(v.x) | ((uint32_t)f2bf(v.y) << 16);
  uint32_t hi = f2bf(v.z) | ((uint32_t)f2bf(v.w) << 16);
  ((uint2*)out)[i] = make_uint2(lo, hi);
}

// transpose + convert the 4 weight matrices [1024x1024] f32 -> WT[n][k] bf16
__global__ void k_tc(const float* __restrict__ W0, const float* __restrict__ W1,
                     const float* __restrict__ W2, const float* __restrict__ W3,
                     u16* __restrict__ dst) {
  __shared__ float t[64][65];
  const float* W = blockIdx.z == 0 ? W0 : blockIdx.z == 1 ? W1 : blockIdx.z == 2 ? W2 : W3;
  u16* WT = dst + (size_t)blockIdx.z * (1024 * 1024);
  int c0 = blockIdx.x * 64, r0 = blockIdx.y * 64;
  int c = threadIdx.x & 63, q = threadIdx.x >> 6;
  for (int r = q; r < 64; r += 4) t[r][c] = W[(size_t)(r0 + r) * 1024 + c0 + c];
  __syncthreads();
  for (int r = q; r < 64; r += 4) WT[(size_t)(c0 + r) * 1024 + r0 + c] = f2bf(t[c][r]);
}

struct GArgs {
  const u16* A; const u16* B; int lda, ldb; long long bstrideB; int K;
  const float* bias; const float* adj; float* dpart; const float* dpart_r;
  void* C; int ldc;
  const u16* A1; const u16* B1; const u16* B2;
  const float* bias1; const float* bias2; void* C1; void* C2;
};

// m97 structure, occupancy-first: 128x128 tile, BK=64, 4 waves (2x2),
// per-wave 64x64 (4x4 16x16x32 MFMA). LDS 32KB single-buffered ->
// 4 blocks/CU resident; latency hidden by INTER-BLOCK overlap (m114).
// LDS tiles [128][64] u16, XOR swizzle phys_u16col = c ^ ((row&7)<<3);
// staged via linear gload_lds dest + inverse-swizzled global source.
// Measured (r8): PROJ 817 TF, EXP 546 TF (incl. compulsory 64MB adj read).
template <int MODE>
__global__ __launch_bounds__(256, 4) void gemm_occ(GArgs g) {
  __shared__ __align__(16) u16 As[128 * 64];
  __shared__ __align__(16) u16 Bs[128 * 64];

  const int tid = threadIdx.x;
  const int lane = tid & 63;
  const int wid = tid >> 6;
  const int wr = wid >> 1, wc = wid & 1;

  const int m0 = blockIdx.x * 128;
  const int n0 = blockIdx.y * 128;
  const int b = m0 >> 11;  // 2048 rows per batch

  const u16* A = g.A; const u16* B = g.B;
  const float* bias = g.bias; void* C = g.C;
  int zmode = 0;
  if constexpr (MODE == M_PROJ) {
    int z = blockIdx.z; zmode = z;
    if (z == 1) { A = g.A1; B = g.B1; bias = g.bias1; C = g.C1; }
    else if (z == 2) { A = g.A1; B = g.B2; bias = g.bias2; C = g.C2; }
  }
  const int lda = g.lda, ldb = g.ldb, K = g.K;
  const u16* Bp = B + (size_t)b * g.bstrideB;

  f32x4 acc[4][4] = {};

  const int ric = lane >> 3;         // row within 8-row chunk
  const int c8 = (lane & 7) * 8;     // u16 col granule (16B)
  const int fr = lane & 15;
  const int hi = lane >> 4;

  for (int kt = 0; kt < K; kt += 64) {
#pragma unroll
    for (int c = 0; c < 4; ++c) {
      int ch = wid * 4 + c;          // 16 chunks of 8 rows x 128B
      int row = ch * 8 + ric;
      int swc = c8 ^ ((row & 7) << 3);  // inverse-swizzled source col
      gload_lds16(A + (size_t)(m0 + row) * lda + kt + swc, (void*)&As[ch * 512]);
      gload_lds16(Bp + (size_t)(n0 + row) * ldb + kt + swc, (void*)&Bs[ch * 512]);
    }
    __syncthreads();
#pragma unroll
    for (int kk = 0; kk < 64; kk += 32) {
      bf16x8 af[4], bfr[4];
#pragma unroll
      for (int m = 0; m < 4; ++m) {
        int row = wr * 64 + m * 16 + fr;
        af[m] = *(const bf16x8*)__builtin_assume_aligned(
            &As[row * 64 + ((kk + hi * 8) ^ ((row & 7) << 3))], 16);
      }
#pragma unroll
      for (int n = 0; n < 4; ++n) {
        int row = wc * 64 + n * 16 + fr;
        bfr[n] = *(const bf16x8*)__builtin_assume_aligned(
            &Bs[row * 64 + ((kk + hi * 8) ^ ((row & 7) << 3))], 16);
      }
#pragma unroll
      for (int m = 0; m < 4; ++m)
#pragma unroll
        for (int n = 0; n < 4; ++n)
          acc[m][n] = __builtin_amdgcn_mfma_f32_16x16x32_bf16(af[m], bfr[n], acc[m][n], 0, 0, 0);
    }
    __syncthreads();
  }

  // C layout (m89-verified): col = lane&15, row = (lane>>4)*4 + reg
  const int lr = lane >> 4;
  const int lc = lane & 15;

  if constexpr (MODE == M_PROJ) {
    if (zmode < 2) {
      u16* Cc = (u16*)C;
#pragma unroll
      for (int m = 0; m < 4; ++m)
#pragma unroll
        for (int n = 0; n < 4; ++n) {
          int gcol = n0 + wc * 64 + n * 16 + lc;
          float bv = bias[gcol];
#pragma unroll
          for (int r = 0; r < 4; ++r) {
            int grow = m0 + wr * 64 + m * 16 + lr * 4 + r;
            Cc[(size_t)grow * g.ldc + gcol] = f2bf(acc[m][n][r] + bv);
          }
        }
    } else {  // V: store transposed Vt[b][d][t]
      u16* Cc = (u16*)C;
#pragma unroll
      for (int m = 0; m < 4; ++m) {
        int grow0 = m0 + wr * 64 + m * 16 + lr * 4;
        int t0 = grow0 & 2047;
#pragma unroll
        for (int n = 0; n < 4; ++n) {
          int gcol = n0 + wc * 64 + n * 16 + lc;
          float bv = bias[gcol];
          ushort4 pk = make_ushort4(f2bf(acc[m][n][0] + bv), f2bf(acc[m][n][1] + bv),
                                    f2bf(acc[m][n][2] + bv), f2bf(acc[m][n][3] + bv));
          *(ushort4*)&Cc[((size_t)b * 1024 + gcol) * 2048 + t0] = pk;
        }
      }
    }
  } else if constexpr (MODE == M_EXP) {
    u16* Cc = (u16*)C;  // E [8192][2048]
    float esum[4][4] = {};
#pragma unroll
    for (int m = 0; m < 4; ++m)
#pragma unroll
      for (int n = 0; n < 4; ++n) {
        int gcol = n0 + wc * 64 + n * 16 + lc;
#pragma unroll
        for (int r = 0; r < 4; ++r) {
          int grow = m0 + wr * 64 + m * 16 + lr * 4 + r;
          float z = acc[m][n][r] * NORM + g.adj[(size_t)grow * 2048 + gcol];
          float e = __expf(z);
          Cc[(size_t)grow * 2048 + gcol] = f2bf(e);
          esum[m][r] += e;
        }
      }
    int pidx = blockIdx.y * 2 + wc;  // 16 t-tiles x 2 wave-cols = 32 partials
#pragma unroll
    for (int m = 0; m < 4; ++m)
#pragma unroll
      for (int r = 0; r < 4; ++r) {
        float s = esum[m][r];
        s += __shfl_xor(s, 1); s += __shfl_xor(s, 2);
        s += __shfl_xor(s, 4); s += __shfl_xor(s, 8);
        if (lc == 0)
          g.dpart[(size_t)pidx * 8192 + (m0 + wr * 64 + m * 16 + lr * 4 + r)] = s;
      }
  }
}

// ---------- 128x64 tile, 4 waves (each 32m x 64n): PV & OUT ----------
// Full-residency variant for the narrow-N GEMMs: grid (64,16) = 1024
// blocks -> 4 blocks/CU everywhere (measured r9). LDS 24KB.
template <int MODE2>
__global__ __launch_bounds__(256, 4) void gemm64(GArgs g) {
  __shared__ __align__(16) u16 As[128 * 64];
  __shared__ __align__(16) u16 Bs[64 * 64];

  const int tid = threadIdx.x;
  const int lane = tid & 63;
  const int wid = tid >> 6;

  int bx = blockIdx.x, by = blockIdx.y;
  remap1024(bx, by);
  const int m0 = bx * 128;
  const int n0 = by * 64;
  const int b = m0 >> 11;

  const int lda = g.lda, ldb = g.ldb, K = g.K;
  const u16* Bp = g.B + (size_t)b * g.bstrideB;

  f32x4 acc[2][4] = {};

  const int ric = lane >> 3;
  const int c8 = (lane & 7) * 8;
  const int fr = lane & 15;
  const int hi = lane >> 4;

  for (int kt = 0; kt < K; kt += 64) {
#pragma unroll
    for (int c = 0; c < 4; ++c) {
      int ch = wid * 4 + c;          // A: 16 chunks
      int row = ch * 8 + ric;
      int swc = c8 ^ ((row & 7) << 3);
      gload_lds16(g.A + (size_t)(m0 + row) * lda + kt + swc, (void*)&As[ch * 512]);
    }
#pragma unroll
    for (int c = 0; c < 2; ++c) {
      int ch = wid * 2 + c;          // B: 8 chunks
      int row = ch * 8 + ric;
      int swc = c8 ^ ((row & 7) << 3);
      gload_lds16(Bp + (size_t)(n0 + row) * ldb + kt + swc, (void*)&Bs[ch * 512]);
    }
    __syncthreads();
#pragma unroll
    for (int kk = 0; kk < 64; kk += 32) {
      bf16x8 af[2], bfr[4];
#pragma unroll
      for (int m = 0; m < 2; ++m) {
        int row = wid * 32 + m * 16 + fr;
        af[m] = *(const bf16x8*)__builtin_assume_aligned(
            &As[row * 64 + ((kk + hi * 8) ^ ((row & 7) << 3))], 16);
      }
#pragma unroll
      for (int n = 0; n < 4; ++n) {
        int row = n * 16 + fr;
        bfr[n] = *(const bf16x8*)__builtin_assume_aligned(
            &Bs[row * 64 + ((kk + hi * 8) ^ ((row & 7) << 3))], 16);
      }
#pragma unroll
      for (int m = 0; m < 2; ++m)
#pragma unroll
        for (int n = 0; n < 4; ++n)
          acc[m][n] = __builtin_amdgcn_mfma_f32_16x16x32_bf16(af[m], bfr[n], acc[m][n], 0, 0, 0);
    }
    __syncthreads();
  }

  const int lr = lane >> 4;
  const int lc = lane & 15;

  if constexpr (MODE2 == M_PV) {
    __shared__ float dinv[128];
    if (tid < 128) {
      float s = 0.f;
#pragma unroll
      for (int t = 0; t < 32; ++t) s += g.dpart_r[(size_t)t * 8192 + m0 + tid];
      dinv[tid] = 1.0f / s;
    }
    __syncthreads();
    u16* Cc = (u16*)g.C;
#pragma unroll
    for (int m = 0; m < 2; ++m)
#pragma unroll
      for (int n = 0; n < 4; ++n) {
        int gcol = n0 + n * 16 + lc;
#pragma unroll
        for (int r = 0; r < 4; ++r) {
          int lrow = wid * 32 + m * 16 + lr * 4 + r;
          Cc[(size_t)(m0 + lrow) * g.ldc + gcol] = f2bf(acc[m][n][r] * dinv[lrow]);
        }
      }
  } else {  // M_OUT: f32 + bias
    float* Cc = (float*)g.C;
#pragma unroll
    for (int m = 0; m < 2; ++m)
#pragma unroll
      for (int n = 0; n < 4; ++n) {
        int gcol = n0 + n * 16 + lc;
        float bv = g.bias[gcol];
#pragma unroll
        for (int r = 0; r < 4; ++r) {
          int grow = m0 + wid * 32 + m * 16 + lr * 4 + r;
          Cc[(size_t)grow * g.ldc + gcol] = acc[m][n][r] + bv;
        }
      }
  }
}

extern "C" void kernel_launch(void* const* d_in, const int* in_sizes, int n_in,
                              void* d_out, int out_size, void* d_ws, size_t ws_size,
                              hipStream_t stream) {
  const float* x   = (const float*)d_in[0];
  const float* y   = (const float*)d_in[1];
  const float* adj = (const float*)d_in[2];
  const float* Wq  = (const float*)d_in[3];
  const float* bq  = (const float*)d_in[4];
  const float* Wk  = (const float*)d_in[5];
  const float* bk  = (const float*)d_in[6];
  const float* Wv  = (const float*)d_in[7];
  const float* bv  = (const float*)d_in[8];
  const float* Wo  = (const float*)d_in[9];
  const float* bo  = (const float*)d_in[10];
  float* out = (float*)d_out;

  char* ws = (char*)d_ws;
  if (ws_size < 143654912ULL) return;  // need ~137 MB
  u16* xb = (u16*)(ws);                 // [8192][1024] bf16
  u16* yb = (u16*)(ws + 16777216);      // [8192][1024]
  u16* WT = (u16*)(ws + 33554432);      // 4 x [1024][1024] (transposed)
  u16* Qb = (u16*)(ws + 41943040);      // [8192][1024]
  u16* Kb = (u16*)(ws + 58720256);      // [8192][1024]
  u16* Vt = (u16*)(ws + 75497472);      // [4][1024][2048] (V transposed)
  u16* E  = (u16*)(ws + 92274688);      // [8192][2048] unnormalized exp
  float* dpart = (float*)(ws + 125829120);  // [32][8192] partial denoms
  u16* tmpb = (u16*)(ws + 126877696);   // [8192][1024] attention output

  u16* WqT = WT;
  u16* WkT = WT + 1048576;
  u16* WvT = WT + 2097152;
  u16* WoT = WT + 3145728;

  k_cvt<<<8192, 256, 0, stream>>>(x, xb, 2097152);
  k_cvt<<<8192, 256, 0, stream>>>(y, yb, 2097152);
  k_tc<<<dim3(16, 16, 4), 256, 0, stream>>>(Wq, Wk, Wv, Wo, WT);

  GArgs ga = {};
  // fused Q/K/V projections (z selects); 64x8x3 = 1536 blocks
  ga.A = xb; ga.B = WqT; ga.lda = 1024; ga.ldb = 1024; ga.bstrideB = 0; ga.K = 1024;
  ga.bias = bq; ga.C = Qb; ga.ldc = 1024;
  ga.A1 = yb; ga.B1 = WkT; ga.B2 = WvT; ga.bias1 = bk; ga.bias2 = bv;
  ga.C1 = Kb; ga.C2 = Vt;
  gemm_occ<M_PROJ><<<dim3(64, 8, 3), 256, 0, stream>>>(ga);

  // E = exp(Q@K^T * norm + adj), partial row sums; 64x16 = 1024 blocks
  GArgs ge = {};
  ge.A = Qb; ge.B = Kb; ge.lda = 1024; ge.ldb = 1024; ge.bstrideB = 2097152LL; ge.K = 1024;
  ge.adj = adj; ge.dpart = dpart; ge.C = E; ge.ldc = 2048;
  gemm_occ<M_EXP><<<dim3(64, 16), 256, 0, stream>>>(ge);

  // tmp = (E @ V) / denom; (64,16) = 1024 blocks (128x64 tiles)
  GArgs gp = {};
  gp.A = E; gp.B = Vt; gp.lda = 2048; gp.ldb = 2048; gp.bstrideB = 2097152LL; gp.K = 2048;
  gp.dpart_r = dpart; gp.C = tmpb; gp.ldc = 1024;
  gemm64<M_PV><<<dim3(64, 16), 256, 0, stream>>>(gp);

  // out = tmp @ Wo + bo (f32); (64,16) = 1024 blocks (128x64 tiles)
  GArgs go = {};
  go.A = tmpb; go.B = WoT; go.lda = 1024; go.ldb = 1024; go.bstrideB = 0; go.K = 1024;
  go.bias = bo; go.C = out; go.ldc = 1024;
  gemm64<M_OUT><<<dim3(64, 16), 256, 0, stream>>>(go);
}

// Round 14
// 217.593 us; speedup vs baseline: 1.3256x; 1.1784x over previous
//
#include <hip/hip_runtime.h>
#include <stdint.h>

typedef unsigned short u16;
using bf16x8 = __attribute__((ext_vector_type(8))) short;
using f32x4  = __attribute__((ext_vector_type(4))) float;

#define NORM 0.03125f  // 1/sqrt(1024)

enum { M_PROJ = 0, M_EXP = 1, M_PV = 2, M_OUT = 3 };

__device__ __forceinline__ u16 f2bf(float f) {
  uint32_t u = __float_as_uint(f);
  return (u16)((u + 0x7FFFu + ((u >> 16) & 1u)) >> 16);  // RNE
}

__device__ __forceinline__ void gload_lds16(const void* g, void* lds) {
  __builtin_amdgcn_global_load_lds(
      (const __attribute__((address_space(1))) uint32_t*)g,
      (__attribute__((address_space(3))) uint32_t*)lds, 16, 0, 0);
}

// f32 -> bf16 elementwise, 4 elems/thread
__global__ void k_cvt(const float* __restrict__ in, u16* __restrict__ out, int n4) {
  int i = blockIdx.x * blockDim.x + threadIdx.x;
  if (i >= n4) return;
  float4 v = ((const float4*)in)[i];
  uint32_t lo = f2bf(v.x) | ((uint32_t)f2bf(v.y) << 16);
  uint32_t hi = f2bf(v.z) | ((uint32_t)f2bf(v.w) << 16);
  ((uint2*)out)[i] = make_uint2(lo, hi);
}

// transpose + convert the 4 weight matrices [1024x1024] f32 -> WT[n][k] bf16
__global__ void k_tc(const float* __restrict__ W0, const float* __restrict__ W1,
                     const float* __restrict__ W2, const float* __restrict__ W3,
                     u16* __restrict__ dst) {
  __shared__ float t[64][65];
  const float* W = blockIdx.z == 0 ? W0 : blockIdx.z == 1 ? W1 : blockIdx.z == 2 ? W2 : W3;
  u16* WT = dst + (size_t)blockIdx.z * (1024 * 1024);
  int c0 = blockIdx.x * 64, r0 = blockIdx.y * 64;
  int c = threadIdx.x & 63, q = threadIdx.x >> 6;
  for (int r = q; r < 64; r += 4) t[r][c] = W[(size_t)(r0 + r) * 1024 + c0 + c];
  __syncthreads();
  for (int r = q; r < 64; r += 4) WT[(size_t)(c0 + r) * 1024 + r0 + c] = f2bf(t[c][r]);
}

struct GArgs {
  const u16* A; const u16* B; int lda, ldb; long long bstrideB; int K;
  const float* bias; const float* adj; float* dpart; const float* dpart_r;
  void* C; int ldc;
  const u16* A1; const u16* B1; const u16* B2;
  const float* bias1; const float* bias2; void* C1; void* C2;
};

// m97 structure, occupancy-first: 128x128 tile, BK=64, 4 waves (2x2),
// per-wave 64x64 (4x4 16x16x32 MFMA). LDS 32KB single-buffered ->
// 4 blocks/CU resident (VGPR 64, launch_bounds(256,4)); latency hidden by
// INTER-BLOCK overlap (m114), not intra-block pipelining (5 schedule
// variants measured neutral-to-negative, r4-r9).
// LDS tiles [128][64] u16, XOR swizzle phys_u16col = c ^ ((row&7)<<3);
// staged via linear gload_lds dest + inverse-swizzled global source
// (both-sides involution). Bank conflicts: 0 (measured).
// Default dispatch order everywhere: every hand XCD-remap measured worse
// (bx-major chunking streams full A per XCD -> L2 thrash, r10/r11/r13).
// Measured per-pass (r8): PROJ 817 TF, EXP 546 TF (incl. 64MB adj read),
// PV 625 TF, OUT 452 TF -> composite 219 us.
template <int MODE>
__global__ __launch_bounds__(256, 4) void gemm_occ(GArgs g) {
  __shared__ __align__(16) u16 As[128 * 64];
  __shared__ __align__(16) u16 Bs[128 * 64];

  const int tid = threadIdx.x;
  const int lane = tid & 63;
  const int wid = tid >> 6;
  const int wr = wid >> 1, wc = wid & 1;

  const int m0 = blockIdx.x * 128;
  const int n0 = blockIdx.y * 128;
  const int b = m0 >> 11;  // 2048 rows per batch

  const u16* A = g.A; const u16* B = g.B;
  const float* bias = g.bias; void* C = g.C;
  int zmode = 0;
  if constexpr (MODE == M_PROJ) {
    int z = blockIdx.z; zmode = z;
    if (z == 1) { A = g.A1; B = g.B1; bias = g.bias1; C = g.C1; }
    else if (z == 2) { A = g.A1; B = g.B2; bias = g.bias2; C = g.C2; }
  }
  const int lda = g.lda, ldb = g.ldb, K = g.K;
  const u16* Bp = B + (size_t)b * g.bstrideB;

  f32x4 acc[4][4] = {};

  const int ric = lane >> 3;         // row within 8-row chunk
  const int c8 = (lane & 7) * 8;     // u16 col granule (16B)
  const int fr = lane & 15;
  const int hi = lane >> 4;

  for (int kt = 0; kt < K; kt += 64) {
#pragma unroll
    for (int c = 0; c < 4; ++c) {
      int ch = wid * 4 + c;          // 16 chunks of 8 rows x 128B
      int row = ch * 8 + ric;
      int swc = c8 ^ ((row & 7) << 3);  // inverse-swizzled source col
      gload_lds16(A + (size_t)(m0 + row) * lda + kt + swc, (void*)&As[ch * 512]);
      gload_lds16(Bp + (size_t)(n0 + row) * ldb + kt + swc, (void*)&Bs[ch * 512]);
    }
    __syncthreads();
#pragma unroll
    for (int kk = 0; kk < 64; kk += 32) {
      bf16x8 af[4], bfr[4];
#pragma unroll
      for (int m = 0; m < 4; ++m) {
        int row = wr * 64 + m * 16 + fr;
        af[m] = *(const bf16x8*)__builtin_assume_aligned(
            &As[row * 64 + ((kk + hi * 8) ^ ((row & 7) << 3))], 16);
      }
#pragma unroll
      for (int n = 0; n < 4; ++n) {
        int row = wc * 64 + n * 16 + fr;
        bfr[n] = *(const bf16x8*)__builtin_assume_aligned(
            &Bs[row * 64 + ((kk + hi * 8) ^ ((row & 7) << 3))], 16);
      }
#pragma unroll
      for (int m = 0; m < 4; ++m)
#pragma unroll
        for (int n = 0; n < 4; ++n)
          acc[m][n] = __builtin_amdgcn_mfma_f32_16x16x32_bf16(af[m], bfr[n], acc[m][n], 0, 0, 0);
    }
    __syncthreads();
  }

  // C layout (m89-verified): col = lane&15, row = (lane>>4)*4 + reg
  const int lr = lane >> 4;
  const int lc = lane & 15;

  if constexpr (MODE == M_PROJ) {
    if (zmode < 2) {
      u16* Cc = (u16*)C;
#pragma unroll
      for (int m = 0; m < 4; ++m)
#pragma unroll
        for (int n = 0; n < 4; ++n) {
          int gcol = n0 + wc * 64 + n * 16 + lc;
          float bv = bias[gcol];
#pragma unroll
          for (int r = 0; r < 4; ++r) {
            int grow = m0 + wr * 64 + m * 16 + lr * 4 + r;
            Cc[(size_t)grow * g.ldc + gcol] = f2bf(acc[m][n][r] + bv);
          }
        }
    } else {  // V: store transposed Vt[b][d][t]
      u16* Cc = (u16*)C;
#pragma unroll
      for (int m = 0; m < 4; ++m) {
        int grow0 = m0 + wr * 64 + m * 16 + lr * 4;
        int t0 = grow0 & 2047;
#pragma unroll
        for (int n = 0; n < 4; ++n) {
          int gcol = n0 + wc * 64 + n * 16 + lc;
          float bv = bias[gcol];
          ushort4 pk = make_ushort4(f2bf(acc[m][n][0] + bv), f2bf(acc[m][n][1] + bv),
                                    f2bf(acc[m][n][2] + bv), f2bf(acc[m][n][3] + bv));
          *(ushort4*)&Cc[((size_t)b * 1024 + gcol) * 2048 + t0] = pk;
        }
      }
    }
  } else if constexpr (MODE == M_EXP) {
    u16* Cc = (u16*)C;  // E [8192][2048]
    float esum[4][4] = {};
#pragma unroll
    for (int m = 0; m < 4; ++m)
#pragma unroll
      for (int n = 0; n < 4; ++n) {
        int gcol = n0 + wc * 64 + n * 16 + lc;
#pragma unroll
        for (int r = 0; r < 4; ++r) {
          int grow = m0 + wr * 64 + m * 16 + lr * 4 + r;
          float z = acc[m][n][r] * NORM + g.adj[(size_t)grow * 2048 + gcol];
          float e = __expf(z);
          Cc[(size_t)grow * 2048 + gcol] = f2bf(e);
          esum[m][r] += e;
        }
      }
    int pidx = blockIdx.y * 2 + wc;  // 16 t-tiles x 2 wave-cols = 32 partials
#pragma unroll
    for (int m = 0; m < 4; ++m)
#pragma unroll
      for (int r = 0; r < 4; ++r) {
        float s = esum[m][r];
        s += __shfl_xor(s, 1); s += __shfl_xor(s, 2);
        s += __shfl_xor(s, 4); s += __shfl_xor(s, 8);
        if (lc == 0)
          g.dpart[(size_t)pidx * 8192 + (m0 + wr * 64 + m * 16 + lr * 4 + r)] = s;
      }
  } else if constexpr (MODE == M_PV) {
    __shared__ float dinv[128];
    if (tid < 128) {
      float s = 0.f;
#pragma unroll
      for (int t = 0; t < 32; ++t) s += g.dpart_r[(size_t)t * 8192 + m0 + tid];
      dinv[tid] = 1.0f / s;
    }
    __syncthreads();
    u16* Cc = (u16*)C;
#pragma unroll
    for (int m = 0; m < 4; ++m)
#pragma unroll
      for (int n = 0; n < 4; ++n) {
        int gcol = n0 + wc * 64 + n * 16 + lc;
#pragma unroll
        for (int r = 0; r < 4; ++r) {
          int lrow = wr * 64 + m * 16 + lr * 4 + r;
          Cc[(size_t)(m0 + lrow) * g.ldc + gcol] = f2bf(acc[m][n][r] * dinv[lrow]);
        }
      }
  } else {  // M_OUT: f32 + bias
    float* Cc = (float*)C;
#pragma unroll
    for (int m = 0; m < 4; ++m)
#pragma unroll
      for (int n = 0; n < 4; ++n) {
        int gcol = n0 + wc * 64 + n * 16 + lc;
        float bv = bias[gcol];
#pragma unroll
        for (int r = 0; r < 4; ++r) {
          int grow = m0 + wr * 64 + m * 16 + lr * 4 + r;
          Cc[(size_t)grow * g.ldc + gcol] = acc[m][n][r] + bv;
        }
      }
  }
}

extern "C" void kernel_launch(void* const* d_in, const int* in_sizes, int n_in,
                              void* d_out, int out_size, void* d_ws, size_t ws_size,
                              hipStream_t stream) {
  const float* x   = (const float*)d_in[0];
  const float* y   = (const float*)d_in[1];
  const float* adj = (const float*)d_in[2];
  const float* Wq  = (const float*)d_in[3];
  const float* bq  = (const float*)d_in[4];
  const float* Wk  = (const float*)d_in[5];
  const float* bk  = (const float*)d_in[6];
  const float* Wv  = (const float*)d_in[7];
  const float* bv  = (const float*)d_in[8];
  const float* Wo  = (const float*)d_in[9];
  const float* bo  = (const float*)d_in[10];
  float* out = (float*)d_out;

  char* ws = (char*)d_ws;
  if (ws_size < 143654912ULL) return;  // need ~137 MB
  u16* xb = (u16*)(ws);                 // [8192][1024] bf16
  u16* yb = (u16*)(ws + 16777216);      // [8192][1024]
  u16* WT = (u16*)(ws + 33554432);      // 4 x [1024][1024] (transposed)
  u16* Qb = (u16*)(ws + 41943040);      // [8192][1024]
  u16* Kb = (u16*)(ws + 58720256);      // [8192][1024]
  u16* Vt = (u16*)(ws + 75497472);      // [4][1024][2048] (V transposed)
  u16* E  = (u16*)(ws + 92274688);      // [8192][2048] unnormalized exp
  float* dpart = (float*)(ws + 125829120);  // [32][8192] partial denoms
  u16* tmpb = (u16*)(ws + 126877696);   // [8192][1024] attention output

  u16* WqT = WT;
  u16* WkT = WT + 1048576;
  u16* WvT = WT + 2097152;
  u16* WoT = WT + 3145728;

  k_cvt<<<8192, 256, 0, stream>>>(x, xb, 2097152);
  k_cvt<<<8192, 256, 0, stream>>>(y, yb, 2097152);
  k_tc<<<dim3(16, 16, 4), 256, 0, stream>>>(Wq, Wk, Wv, Wo, WT);

  GArgs ga = {};
  // fused Q/K/V projections (z selects); 64x8x3 = 1536 blocks
  ga.A = xb; ga.B = WqT; ga.lda = 1024; ga.ldb = 1024; ga.bstrideB = 0; ga.K = 1024;
  ga.bias = bq; ga.C = Qb; ga.ldc = 1024;
  ga.A1 = yb; ga.B1 = WkT; ga.B2 = WvT; ga.bias1 = bk; ga.bias2 = bv;
  ga.C1 = Kb; ga.C2 = Vt;
  gemm_occ<M_PROJ><<<dim3(64, 8, 3), 256, 0, stream>>>(ga);

  // E = exp(Q@K^T * norm + adj), partial row sums; 64x16 = 1024 blocks
  GArgs ge = {};
  ge.A = Qb; ge.B = Kb; ge.lda = 1024; ge.ldb = 1024; ge.bstrideB = 2097152LL; ge.K = 1024;
  ge.adj = adj; ge.dpart = dpart; ge.C = E; ge.ldc = 2048;
  gemm_occ<M_EXP><<<dim3(64, 16), 256, 0, stream>>>(ge);

  // tmp = (E @ V) / denom; 64x8 = 512 blocks
  GArgs gp = {};
  gp.A = E; gp.B = Vt; gp.lda = 2048; gp.ldb = 2048; gp.bstrideB = 2097152LL; gp.K = 2048;
  gp.dpart_r = dpart; gp.C = tmpb; gp.ldc = 1024;
  gemm_occ<M_PV><<<dim3(64, 8), 256, 0, stream>>>(gp);

  // out = tmp @ Wo + bo (f32); 64x8 = 512 blocks
  GArgs go = {};
  go.A = tmpb; go.B = WoT; go.lda = 1024; go.ldb = 1024; go.bstrideB = 0; go.K = 1024;
  go.bias = bo; go.C = out; go.ldc = 1024;
  gemm_occ<M_OUT><<<dim3(64, 8), 256, 0, stream>>>(go);
}